// Round 3
// baseline (662.219 us; speedup 1.0000x reference)
//
#include <hip/hip_runtime.h>

#define N_NODES    100000
#define N_EDGES    1600000
#define IN_F       64
#define OUT_F      40
#define N_CLUSTERS 10000

#define NCHUNK     4                                  // 4 feature chunks of 16 floats (64 B)
#define BUCK_SHIFT 9                                  // 512 rows per bucket
#define NBUCK      ((N_NODES + 511) >> BUCK_SHIFT)    // 196
#define TILE_E     4096
#define EPT        (TILE_E / 256)                     // 16 edges per thread
#define FILL_SPLIT 8

// ---------------------------------------------------------------- bucket histogram + degree count
__global__ void bucket_hist_kernel(const int* __restrict__ rows, int* __restrict__ bhist,
                                   int* __restrict__ deg) {
    __shared__ int lh[NBUCK];
    int t = threadIdx.x;
    for (int i = t; i < NBUCK; i += 256) lh[i] = 0;
    __syncthreads();
    int e0 = blockIdx.x * TILE_E;
    #pragma unroll
    for (int k = 0; k < EPT; ++k) {
        int e = e0 + t + k * 256;
        if (e < N_EDGES) {
            int r = rows[e];
            atomicAdd(&lh[r >> BUCK_SHIFT], 1);
            atomicAdd(&deg[r], 1);                    // 400 KB window, L2-resident
        }
    }
    __syncthreads();
    for (int i = t; i < NBUCK; i += 256) {
        int c = lh[i];
        if (c) atomicAdd(&bhist[i], c);
    }
}

// ---------------------------------------------------------------- bucket scan (exclusive)
__global__ void bucket_scan_kernel(const int* __restrict__ bhist, int* __restrict__ bbase,
                                   int* __restrict__ bcursor) {
    __shared__ int s[256];
    int t = threadIdx.x;
    int v = (t < NBUCK) ? bhist[t] : 0;
    s[t] = v;
    __syncthreads();
    for (int off = 1; off < 256; off <<= 1) {
        int a = (t >= off) ? s[t - off] : 0;
        __syncthreads();
        s[t] += a;
        __syncthreads();
    }
    if (t < NBUCK) { int ex = s[t] - v; bbase[t] = ex; bcursor[t] = ex; }
    if (t == 0) bbase[NBUCK] = N_EDGES;
}

// ---------------------------------------------------------------- bin scatter (LDS-ordered, coalesced out)
__global__ void bin_scatter_kernel(const int* __restrict__ rows, const int* __restrict__ cols,
                                   int* __restrict__ bcursor, uint2* __restrict__ bins) {
    __shared__ uint2 se[TILE_E];
    __shared__ int lh[NBUCK];
    __shared__ int lsc[NBUCK];
    __shared__ int lb[NBUCK];
    __shared__ int sc[256];
    int t = threadIdx.x;
    for (int i = t; i < NBUCK; i += 256) lh[i] = 0;
    __syncthreads();
    int e0 = blockIdx.x * TILE_E;
    int r[EPT], c[EPT], rk[EPT];
    #pragma unroll
    for (int k = 0; k < EPT; ++k) {
        int e = e0 + t + k * 256;
        if (e < N_EDGES) {
            r[k] = rows[e]; c[k] = cols[e];
            rk[k] = atomicAdd(&lh[r[k] >> BUCK_SHIFT], 1);
        } else r[k] = -1;
    }
    __syncthreads();
    int v = (t < NBUCK) ? lh[t] : 0;
    sc[t] = v;
    __syncthreads();
    for (int off = 1; off < 256; off <<= 1) {
        int a = (t >= off) ? sc[t - off] : 0;
        __syncthreads();
        sc[t] += a;
        __syncthreads();
    }
    if (t < NBUCK) {
        lsc[t] = sc[t] - v;
        lb[t] = v ? atomicAdd(&bcursor[t], v) : 0;
    }
    __syncthreads();
    #pragma unroll
    for (int k = 0; k < EPT; ++k) {
        if (r[k] >= 0) {
            int bu = r[k] >> BUCK_SHIFT;
            se[lsc[bu] + rk[k]] = make_uint2((unsigned)r[k], (unsigned)c[k]);
        }
    }
    __syncthreads();
    #pragma unroll
    for (int k = 0; k < EPT; ++k) {
        int idx = k * 256 + t;
        if (e0 + idx < N_EDGES) {
            uint2 u = se[idx];
            int bu = (int)(u.x >> BUCK_SHIFT);
            bins[lb[bu] + (idx - lsc[bu])] = u;
        }
    }
}

// ---------------------------------------------------------------- dinv + cluster counts
__global__ void dinv_ccnt_kernel(const int* __restrict__ deg, const int* __restrict__ cl,
                                 float* __restrict__ dinv, int* __restrict__ ccnt) {
    int i = blockIdx.x * 256 + threadIdx.x;
    if (i < N_NODES) {
        dinv[i] = rsqrtf((float)(deg[i] + 1));
        atomicAdd(&ccnt[cl[i]], 1);
    }
}

// ---------------------------------------------------------------- node scan (exclusive)
__global__ void scan1_kernel(const int* __restrict__ in, int* __restrict__ out,
                             int* __restrict__ partials, int n) {
    __shared__ int s[256];
    int t = threadIdx.x;
    int i = blockIdx.x * 256 + t;
    int v = (i < n) ? in[i] : 0;
    s[t] = v;
    __syncthreads();
    for (int off = 1; off < 256; off <<= 1) {
        int add = (t >= off) ? s[t - off] : 0;
        __syncthreads();
        s[t] += add;
        __syncthreads();
    }
    if (i < n) out[i] = s[t] - v;
    if (t == 255) partials[blockIdx.x] = s[255];
}

__global__ void scan2_kernel(int* __restrict__ p, int nb) {
    __shared__ int s[512];
    int t = threadIdx.x;
    int v = (t < nb) ? p[t] : 0;
    s[t] = v;
    __syncthreads();
    for (int off = 1; off < 512; off <<= 1) {
        int add = (t >= off) ? s[t - off] : 0;
        __syncthreads();
        s[t] += add;
        __syncthreads();
    }
    if (t < nb) p[t] = s[t] - v;
}

__global__ void scan3_kernel(int* __restrict__ row_start, const int* __restrict__ partials,
                             int* __restrict__ cursor, int n, int total) {
    int i = blockIdx.x * 256 + threadIdx.x;
    if (i < n) {
        int v = row_start[i] + partials[blockIdx.x];
        row_start[i] = v;
        cursor[i] = v;
    }
    if (i == 0) row_start[n] = total;
}

// ---------------------------------------------------------------- CSR fill from bins (L2-local window)
__global__ void bin_fill_kernel(const uint2* __restrict__ bins, const int* __restrict__ bbase,
                                int* __restrict__ cursor, int* __restrict__ csr_col) {
    int b = blockIdx.x / FILL_SPLIT;
    int s = blockIdx.x % FILL_SPLIT;
    int lo = bbase[b], hi = bbase[b + 1];
    int n = hi - lo;
    int chunk = (n + FILL_SPLIT - 1) / FILL_SPLIT;
    int beg = lo + s * chunk;
    int end = min(lo + (s + 1) * chunk, hi);
    for (int i = beg + threadIdx.x; i < end; i += 256) {
        uint2 u = bins[i];
        int pos = atomicAdd(&cursor[u.x], 1);
        csr_col[pos] = (int)u.y;
    }
}

// ---------------------------------------------------------------- chunked hop
// wave = (node, chunk). lane = slot(0..15) x q(0..3); slot = neighbor in flight,
// 4 lanes/slot read a 64 B row chunk as float4. chunk = (blockIdx&7)>>1 -> XCD-pair
// affinity (round-robin dispatch heuristic; affects locality only, not correctness).
// MODE 0: in = x node-major, gather *= dinv[c], out chunk-major, scale d^2
// MODE 1: in/out chunk-major, scale d^2
// MODE 2: in chunk-major, scale d, atomicAdd into xc[cl[node]] (no buf write)
template<int MODE>
__global__ void hop_kernel(const float4* __restrict__ in4, float4* __restrict__ out4,
                           const int* __restrict__ row_start, const int* __restrict__ csr_col,
                           const float* __restrict__ dinv, const int* __restrict__ cl,
                           float* __restrict__ xc) {
    int g = blockIdx.x;                 // 100000 blocks = 25000 node-groups x 4 chunks
    int sl = g & 7;
    int chunk = sl >> 1;
    int ng = ((g >> 3) << 1) | (sl & 1);          // [0, 25000)
    int node = ng * 4 + (threadIdx.x >> 6);
    int lane = threadIdx.x & 63;
    int slot = lane >> 2;
    int q    = lane & 3;
    int beg = row_start[node];
    int end = row_start[node + 1];
    float4 acc = make_float4(0.f, 0.f, 0.f, 0.f);
    if (slot == 0) {                    // self-loop term (z-form)
        if (MODE == 0) {
            float4 v = in4[node * 16 + chunk * 4 + q];
            float d = dinv[node];
            acc.x = v.x * d; acc.y = v.y * d; acc.z = v.z * d; acc.w = v.w * d;
        } else {
            acc = in4[(chunk * N_NODES + node) * 4 + q];
        }
    }
    for (int base = beg; base < end; base += 64) {
        int idx = base + lane;
        int cv = (idx < end) ? csr_col[idx] : 0;
        int lim = end - base;
        #pragma unroll
        for (int b = 0; b < 4; ++b) {
            int j = (b << 4) + slot;
            int c = __shfl(cv, j);
            if (j < lim) {
                float4 v;
                if (MODE == 0) {
                    v = in4[c * 16 + chunk * 4 + q];
                    float dc = dinv[c];
                    v.x *= dc; v.y *= dc; v.z *= dc; v.w *= dc;
                } else {
                    v = in4[(chunk * N_NODES + c) * 4 + q];
                }
                acc.x += v.x; acc.y += v.y; acc.z += v.z; acc.w += v.w;
            }
        }
    }
    // reduce across the 16 slots (lane bits 2..5)
    #pragma unroll
    for (int m = 4; m <= 32; m <<= 1) {
        acc.x += __shfl_xor(acc.x, m); acc.y += __shfl_xor(acc.y, m);
        acc.z += __shfl_xor(acc.z, m); acc.w += __shfl_xor(acc.w, m);
    }
    if (slot == 0) {
        float d = dinv[node];
        if (MODE == 2) {
            acc.x *= d; acc.y *= d; acc.z *= d; acc.w *= d;
            float* p = &xc[cl[node] * IN_F + chunk * 16 + q * 4];
            atomicAdd(p + 0, acc.x); atomicAdd(p + 1, acc.y);
            atomicAdd(p + 2, acc.z); atomicAdd(p + 3, acc.w);
        } else {
            float s = d * d;
            acc.x *= s; acc.y *= s; acc.z *= s; acc.w *= s;
            out4[(chunk * N_NODES + node) * 4 + q] = acc;
        }
    }
}

// ---------------------------------------------------------------- cluster GEMM: h = (xc/cnt) @ W^T + b
__global__ void cluster_gemm_kernel(const float* __restrict__ xc, const int* __restrict__ ccnt,
                                    const float* __restrict__ W, const float* __restrict__ b,
                                    float* __restrict__ h) {
    __shared__ float Ws[OUT_F * 65];
    for (int i = threadIdx.x; i < OUT_F * IN_F; i += 256) {
        Ws[(i >> 6) * 65 + (i & 63)] = W[i];
    }
    __syncthreads();
    int idx = blockIdx.x * 256 + threadIdx.x;
    if (idx >= N_CLUSTERS * OUT_F) return;
    int c = idx / OUT_F;
    int o = idx - c * OUT_F;
    float inv = 1.0f / fmaxf((float)ccnt[c], 1.0f);
    const float* xr = xc + c * IN_F;
    const float* wr = Ws + o * 65;
    float acc = 0.0f;
    #pragma unroll
    for (int k = 0; k < IN_F; ++k) acc += xr[k] * wr[k];
    h[idx] = acc * inv + b[o];
}

// ---------------------------------------------------------------- gather back: out[i] = h[cluster[i]]
__global__ void scatter_out_kernel(const float4* __restrict__ h, const int* __restrict__ cl,
                                   float4* __restrict__ out) {
    int i = blockIdx.x * 256 + threadIdx.x;
    if (i < N_NODES * (OUT_F / 4)) {
        int node = i / 10;
        int q = i - node * 10;
        out[i] = h[cl[node] * 10 + q];
    }
}

// ---------------------------------------------------------------- launch
extern "C" void kernel_launch(void* const* d_in, const int* in_sizes, int n_in,
                              void* d_out, int out_size, void* d_ws, size_t ws_size,
                              hipStream_t stream) {
    const float* x    = (const float*)d_in[0];
    const int*   rows = (const int*)d_in[1];
    const int*   cols = (const int*)d_in[1] + N_EDGES;
    const int*   cl   = (const int*)d_in[2];
    const float* W    = (const float*)d_in[4];
    const float* b    = (const float*)d_in[5];
    float* out = (float*)d_out;

    size_t off = 0;
    auto alloc = [&](size_t elems) -> void* {
        void* p = (char*)d_ws + off * 4;
        off += (elems + 3) & ~(size_t)3;
        return p;
    };
    // zeroed region first (single memset): deg | ccnt | xc_sum | bhist
    int*   deg_cnt = (int*)alloc(N_NODES);
    int*   ccnt    = (int*)alloc(N_CLUSTERS);
    float* xc_sum  = (float*)alloc((size_t)N_CLUSTERS * IN_F);
    int*   bhist   = (int*)alloc(NBUCK);
    size_t zero_elems = off;
    float* dinv      = (float*)alloc(N_NODES);
    int*   row_start = (int*)alloc(N_NODES + 1);
    int*   cursor    = (int*)alloc(N_NODES);
    int*   csr_col   = (int*)alloc(N_EDGES);
    int*   bbase     = (int*)alloc(NBUCK + 1);
    int*   bcursor   = (int*)alloc(NBUCK);
    int*   partials  = (int*)alloc(512);
    float* bufA      = (float*)alloc((size_t)N_NODES * IN_F);  // chunk-major z2
    float* bufB      = (float*)alloc((size_t)N_NODES * IN_F);  // chunk-major z3
    float* h         = (float*)alloc((size_t)N_CLUSTERS * OUT_F);
    uint2* bins      = (uint2*)bufA;   // 12.8 MB alias, consumed by bin_fill before hop1 writes bufA
    (void)ws_size; (void)in_sizes; (void)n_in; (void)out_size;

    hipMemsetAsync(d_ws, 0, zero_elems * 4, stream);

    const int TB = (N_EDGES + TILE_E - 1) / TILE_E;   // 391
    const int NB = (N_NODES + 255) / 256;             // 391
    const int HB = (N_NODES / 4) * NCHUNK;            // 100000 blocks (wave per node-chunk)

    bucket_hist_kernel<<<TB, 256, 0, stream>>>(rows, bhist, deg_cnt);
    bucket_scan_kernel<<<1, 256, 0, stream>>>(bhist, bbase, bcursor);
    bin_scatter_kernel<<<TB, 256, 0, stream>>>(rows, cols, bcursor, bins);
    dinv_ccnt_kernel<<<NB, 256, 0, stream>>>(deg_cnt, cl, dinv, ccnt);
    scan1_kernel<<<NB, 256, 0, stream>>>(deg_cnt, row_start, partials, N_NODES);
    scan2_kernel<<<1, 512, 0, stream>>>(partials, NB);
    scan3_kernel<<<NB, 256, 0, stream>>>(row_start, partials, cursor, N_NODES, N_EDGES);
    bin_fill_kernel<<<NBUCK * FILL_SPLIT, 256, 0, stream>>>(bins, bbase, cursor, csr_col);

    hop_kernel<0><<<HB, 256, 0, stream>>>((const float4*)x, (float4*)bufA,
                                          row_start, csr_col, dinv, cl, xc_sum);
    hop_kernel<1><<<HB, 256, 0, stream>>>((const float4*)bufA, (float4*)bufB,
                                          row_start, csr_col, dinv, cl, xc_sum);
    hop_kernel<2><<<HB, 256, 0, stream>>>((const float4*)bufB, (float4*)nullptr,
                                          row_start, csr_col, dinv, cl, xc_sum);

    cluster_gemm_kernel<<<(N_CLUSTERS * OUT_F + 255) / 256, 256, 0, stream>>>(xc_sum, ccnt, W, b, h);
    scatter_out_kernel<<<(N_NODES * 10 + 255) / 256, 256, 0, stream>>>((const float4*)h, cl, (float4*)out);
}

// Round 4
// 518.227 us; speedup vs baseline: 1.2779x; 1.2779x over previous
//
#include <hip/hip_runtime.h>

#define N_NODES    100000
#define N_EDGES    1600000
#define IN_F       64
#define OUT_F      40
#define N_CLUSTERS 10000

#define BUCK_SHIFT 9                                  // 512 rows per bucket
#define NBUCK      ((N_NODES + 511) >> BUCK_SHIFT)    // 196
#define TILE_E     4096
#define EPT        (TILE_E / 256)                     // 16 edges per thread
#define FILL_SPLIT 8
#define PRO_TILE   256

// ---------------------------------------------------------------- bucket histogram + degree count
__global__ void bucket_hist_kernel(const int* __restrict__ rows, int* __restrict__ bhist,
                                   int* __restrict__ deg) {
    __shared__ int lh[NBUCK];
    int t = threadIdx.x;
    for (int i = t; i < NBUCK; i += 256) lh[i] = 0;
    __syncthreads();
    int e0 = blockIdx.x * TILE_E;
    #pragma unroll
    for (int k = 0; k < EPT; ++k) {
        int e = e0 + t + k * 256;
        if (e < N_EDGES) {
            int r = rows[e];
            atomicAdd(&lh[r >> BUCK_SHIFT], 1);
            atomicAdd(&deg[r], 1);                    // 400 KB window, L2-resident
        }
    }
    __syncthreads();
    for (int i = t; i < NBUCK; i += 256) {
        int c = lh[i];
        if (c) atomicAdd(&bhist[i], c);
    }
}

// ---------------------------------------------------------------- bucket scan (exclusive)
__global__ void bucket_scan_kernel(const int* __restrict__ bhist, int* __restrict__ bbase,
                                   int* __restrict__ bcursor) {
    __shared__ int s[256];
    int t = threadIdx.x;
    int v = (t < NBUCK) ? bhist[t] : 0;
    s[t] = v;
    __syncthreads();
    for (int off = 1; off < 256; off <<= 1) {
        int a = (t >= off) ? s[t - off] : 0;
        __syncthreads();
        s[t] += a;
        __syncthreads();
    }
    if (t < NBUCK) { int ex = s[t] - v; bbase[t] = ex; bcursor[t] = ex; }
    if (t == 0) bbase[NBUCK] = N_EDGES;
}

// ---------------------------------------------------------------- bin scatter (LDS-ordered, coalesced out)
__global__ void bin_scatter_kernel(const int* __restrict__ rows, const int* __restrict__ cols,
                                   int* __restrict__ bcursor, uint2* __restrict__ bins) {
    __shared__ uint2 se[TILE_E];
    __shared__ int lh[NBUCK];
    __shared__ int lsc[NBUCK];
    __shared__ int lb[NBUCK];
    __shared__ int sc[256];
    int t = threadIdx.x;
    for (int i = t; i < NBUCK; i += 256) lh[i] = 0;
    __syncthreads();
    int e0 = blockIdx.x * TILE_E;
    int r[EPT], c[EPT], rk[EPT];
    #pragma unroll
    for (int k = 0; k < EPT; ++k) {
        int e = e0 + t + k * 256;
        if (e < N_EDGES) {
            r[k] = rows[e]; c[k] = cols[e];
            rk[k] = atomicAdd(&lh[r[k] >> BUCK_SHIFT], 1);
        } else r[k] = -1;
    }
    __syncthreads();
    int v = (t < NBUCK) ? lh[t] : 0;
    sc[t] = v;
    __syncthreads();
    for (int off = 1; off < 256; off <<= 1) {
        int a = (t >= off) ? sc[t - off] : 0;
        __syncthreads();
        sc[t] += a;
        __syncthreads();
    }
    if (t < NBUCK) {
        lsc[t] = sc[t] - v;
        lb[t] = v ? atomicAdd(&bcursor[t], v) : 0;
    }
    __syncthreads();
    #pragma unroll
    for (int k = 0; k < EPT; ++k) {
        if (r[k] >= 0) {
            int bu = r[k] >> BUCK_SHIFT;
            se[lsc[bu] + rk[k]] = make_uint2((unsigned)r[k], (unsigned)c[k]);
        }
    }
    __syncthreads();
    #pragma unroll
    for (int k = 0; k < EPT; ++k) {
        int idx = k * 256 + t;
        if (e0 + idx < N_EDGES) {
            uint2 u = se[idx];
            int bu = (int)(u.x >> BUCK_SHIFT);
            bins[lb[bu] + (idx - lsc[bu])] = u;
        }
    }
}

// ---------------------------------------------------------------- dinv + cluster counts
__global__ void dinv_ccnt_kernel(const int* __restrict__ deg, const int* __restrict__ cl,
                                 float* __restrict__ dinv, int* __restrict__ ccnt) {
    int i = blockIdx.x * 256 + threadIdx.x;
    if (i < N_NODES) {
        dinv[i] = rsqrtf((float)(deg[i] + 1));
        atomicAdd(&ccnt[cl[i]], 1);
    }
}

// ---------------------------------------------------------------- node scan (exclusive)
__global__ void scan1_kernel(const int* __restrict__ in, int* __restrict__ out,
                             int* __restrict__ partials, int n) {
    __shared__ int s[256];
    int t = threadIdx.x;
    int i = blockIdx.x * 256 + t;
    int v = (i < n) ? in[i] : 0;
    s[t] = v;
    __syncthreads();
    for (int off = 1; off < 256; off <<= 1) {
        int add = (t >= off) ? s[t - off] : 0;
        __syncthreads();
        s[t] += add;
        __syncthreads();
    }
    if (i < n) out[i] = s[t] - v;
    if (t == 255) partials[blockIdx.x] = s[255];
}

__global__ void scan2_kernel(int* __restrict__ p, int nb) {
    __shared__ int s[512];
    int t = threadIdx.x;
    int v = (t < nb) ? p[t] : 0;
    s[t] = v;
    __syncthreads();
    for (int off = 1; off < 512; off <<= 1) {
        int add = (t >= off) ? s[t - off] : 0;
        __syncthreads();
        s[t] += add;
        __syncthreads();
    }
    if (t < nb) p[t] = s[t] - v;
}

__global__ void scan3_kernel(int* __restrict__ row_start, const int* __restrict__ partials,
                             int* __restrict__ cursor, int n, int total) {
    int i = blockIdx.x * 256 + threadIdx.x;
    if (i < n) {
        int v = row_start[i] + partials[blockIdx.x];
        row_start[i] = v;
        cursor[i] = v;
    }
    if (i == 0) row_start[n] = total;
}

// ---------------------------------------------------------------- CSR fill from bins (L2-local window)
__global__ void bin_fill_kernel(const uint2* __restrict__ bins, const int* __restrict__ bbase,
                                int* __restrict__ cursor, int* __restrict__ csr_col) {
    int b = blockIdx.x / FILL_SPLIT;
    int s = blockIdx.x % FILL_SPLIT;
    int lo = bbase[b], hi = bbase[b + 1];
    int n = hi - lo;
    int chunk = (n + FILL_SPLIT - 1) / FILL_SPLIT;
    int beg = lo + s * chunk;
    int end = min(lo + (s + 1) * chunk, hi);
    for (int i = beg + threadIdx.x; i < end; i += 256) {
        uint2 u = bins[i];
        int pos = atomicAdd(&cursor[u.x], 1);
        csr_col[pos] = (int)u.y;
    }
}

// ---------------------------------------------------------------- prologue: z0 = dinv * (x @ W^T)
// tile 256 nodes/block; thread = (wave og = outs og*10..+9) x (nq = node quad).
union ProLds {
    float4 xs[PRO_TILE * 16];     // 64 KB, xor-swizzled on k4
    float  zs[PRO_TILE * 41];     // 42 KB (stride 41 breaks bank aliasing)
};
__global__ __launch_bounds__(256) void prologue_kernel(
        const float4* __restrict__ x4, const float4* __restrict__ W4,
        const float* __restrict__ dinv, float* __restrict__ z0) {
    __shared__ float4 Ws4[OUT_F * 16];   // [o][k4]
    __shared__ ProLds u;
    int t = threadIdx.x;
    int tile = blockIdx.x * PRO_TILE;
    for (int i = t; i < OUT_F * 16; i += 256) Ws4[i] = W4[i];
    #pragma unroll
    for (int k = 0; k < 16; ++k) {
        int i = t + k * 256;
        int n = i >> 4, k4 = i & 15;
        float4 v = make_float4(0.f, 0.f, 0.f, 0.f);
        if (tile + n < N_NODES) v = x4[(tile + n) * 16 + k4];
        u.xs[n * 16 + (k4 ^ (n & 15))] = v;
    }
    __syncthreads();
    int og = t >> 6;          // wave-uniform output group
    int nq = t & 63;          // node quad within tile
    float acc[4][10];
    #pragma unroll
    for (int j = 0; j < 4; ++j)
        #pragma unroll
        for (int i = 0; i < 10; ++i) acc[j][i] = 0.f;
    #pragma unroll
    for (int k4 = 0; k4 < 16; ++k4) {
        float4 xv[4];
        #pragma unroll
        for (int j = 0; j < 4; ++j) {
            int n = nq * 4 + j;
            xv[j] = u.xs[n * 16 + (k4 ^ (n & 15))];
        }
        #pragma unroll
        for (int i = 0; i < 10; ++i) {
            float4 wv = Ws4[(og * 10 + i) * 16 + k4];
            #pragma unroll
            for (int j = 0; j < 4; ++j) {
                acc[j][i] += xv[j].x * wv.x + xv[j].y * wv.y
                           + xv[j].z * wv.z + xv[j].w * wv.w;
            }
        }
    }
    __syncthreads();          // xs dead, reuse as zs
    #pragma unroll
    for (int j = 0; j < 4; ++j)
        #pragma unroll
        for (int i = 0; i < 10; ++i)
            u.zs[(nq * 4 + j) * 41 + og * 10 + i] = acc[j][i];
    __syncthreads();
    for (int i = t; i < PRO_TILE * OUT_F; i += 256) {
        int n = i / OUT_F;
        int o = i - n * OUT_F;
        int gn = tile + n;
        if (gn < N_NODES) z0[gn * OUT_F + o] = u.zs[n * 41 + o] * dinv[gn];
    }
}

// ---------------------------------------------------------------- 40-dim hop
// wave per node; lane = slot(0..5) x ql(0..9), float4 per lane => 160 B row per slot.
// FINAL=0: out = dinv^2 * ((A+I) z), store.  FINAL=1: dinv scale, atomicAdd into xc[cl].
template<int FINAL>
__global__ __launch_bounds__(256) void hop40_kernel(
        const float4* __restrict__ in4, float4* __restrict__ out4,
        const int* __restrict__ row_start, const int* __restrict__ csr_col,
        const float* __restrict__ dinv, const int* __restrict__ cl,
        float* __restrict__ xc) {
    int node = (blockIdx.x << 2) + (threadIdx.x >> 6);
    int lane = threadIdx.x & 63;
    int slot = lane / 10;                 // 6 => idle lanes 60..63 (still shfl sources)
    int ql = lane - slot * 10;
    int slotj = (slot < 6) ? slot : 1000; // idle slots never pass the j<lim guard
    int beg = row_start[node];
    int end = row_start[node + 1];
    float4 acc = make_float4(0.f, 0.f, 0.f, 0.f);
    if (slot == 0) acc = in4[node * 10 + ql];        // self-loop term
    for (int base = beg; base < end; base += 64) {
        int idx = base + lane;
        int cv = (idx < end) ? csr_col[idx] : 0;
        int lim = min(64, end - base);
        #pragma unroll
        for (int r = 0; r < 11; ++r) {
            int j = r * 6 + slotj;
            int c = __shfl(cv, j & 63);
            if (j < lim) {
                float4 v = in4[c * 10 + ql];
                acc.x += v.x; acc.y += v.y; acc.z += v.z; acc.w += v.w;
            }
        }
    }
    // reduce slots: lanes<30 fold +30; then lanes<10 fold +10 and +20
    float4 t1;
    t1.x = __shfl(acc.x, (lane + 30) & 63); t1.y = __shfl(acc.y, (lane + 30) & 63);
    t1.z = __shfl(acc.z, (lane + 30) & 63); t1.w = __shfl(acc.w, (lane + 30) & 63);
    if (lane < 30) { acc.x += t1.x; acc.y += t1.y; acc.z += t1.z; acc.w += t1.w; }
    float4 t2, t3;
    t2.x = __shfl(acc.x, (lane + 10) & 63); t2.y = __shfl(acc.y, (lane + 10) & 63);
    t2.z = __shfl(acc.z, (lane + 10) & 63); t2.w = __shfl(acc.w, (lane + 10) & 63);
    t3.x = __shfl(acc.x, (lane + 20) & 63); t3.y = __shfl(acc.y, (lane + 20) & 63);
    t3.z = __shfl(acc.z, (lane + 20) & 63); t3.w = __shfl(acc.w, (lane + 20) & 63);
    if (lane < 10) {
        acc.x += t2.x + t3.x; acc.y += t2.y + t3.y;
        acc.z += t2.z + t3.z; acc.w += t2.w + t3.w;
        float d = dinv[node];
        if (FINAL) {
            float* p = xc + cl[node] * OUT_F + ql * 4;
            atomicAdd(p + 0, acc.x * d); atomicAdd(p + 1, acc.y * d);
            atomicAdd(p + 2, acc.z * d); atomicAdd(p + 3, acc.w * d);
        } else {
            float s = d * d;
            acc.x *= s; acc.y *= s; acc.z *= s; acc.w *= s;
            out4[node * 10 + ql] = acc;
        }
    }
}

// ---------------------------------------------------------------- epilogue: out[n] = xc[cl[n]]/cnt + b
__global__ void epilogue_kernel(const float4* __restrict__ xc4, const int* __restrict__ ccnt,
                                const float4* __restrict__ b4, const int* __restrict__ cl,
                                float4* __restrict__ out4) {
    int i = blockIdx.x * 256 + threadIdx.x;
    if (i >= N_NODES * (OUT_F / 4)) return;
    int node = i / 10;
    int q = i - node * 10;
    int c = cl[node];
    float inv = 1.0f / fmaxf((float)ccnt[c], 1.0f);
    float4 v = xc4[c * 10 + q];
    float4 bb = b4[q];
    v.x = v.x * inv + bb.x; v.y = v.y * inv + bb.y;
    v.z = v.z * inv + bb.z; v.w = v.w * inv + bb.w;
    out4[i] = v;
}

// ---------------------------------------------------------------- launch
extern "C" void kernel_launch(void* const* d_in, const int* in_sizes, int n_in,
                              void* d_out, int out_size, void* d_ws, size_t ws_size,
                              hipStream_t stream) {
    const float* x    = (const float*)d_in[0];
    const int*   rows = (const int*)d_in[1];
    const int*   cols = (const int*)d_in[1] + N_EDGES;
    const int*   cl   = (const int*)d_in[2];
    const float* W    = (const float*)d_in[4];
    const float* b    = (const float*)d_in[5];
    float* out = (float*)d_out;

    size_t off = 0;
    auto alloc = [&](size_t elems) -> void* {
        void* p = (char*)d_ws + off * 4;
        off += (elems + 3) & ~(size_t)3;
        return p;
    };
    // zeroed region first (single memset): deg | ccnt | xc_sum | bhist
    int*   deg_cnt = (int*)alloc(N_NODES);
    int*   ccnt    = (int*)alloc(N_CLUSTERS);
    float* xc_sum  = (float*)alloc((size_t)N_CLUSTERS * OUT_F);
    int*   bhist   = (int*)alloc(NBUCK);
    size_t zero_elems = off;
    float* dinv      = (float*)alloc(N_NODES);
    int*   row_start = (int*)alloc(N_NODES + 1);
    int*   cursor    = (int*)alloc(N_NODES);
    int*   csr_col   = (int*)alloc(N_EDGES);
    int*   bbase     = (int*)alloc(NBUCK + 1);
    int*   bcursor   = (int*)alloc(NBUCK);
    int*   partials  = (int*)alloc(512);
    float* bufA      = (float*)alloc((size_t)N_NODES * OUT_F);  // 16 MB
    float* bufB      = (float*)alloc((size_t)N_NODES * OUT_F);  // 16 MB
    uint2* bins      = (uint2*)bufA;   // 12.8 MB alias; consumed by bin_fill before hop1 writes bufA
    (void)ws_size; (void)in_sizes; (void)n_in; (void)out_size;

    hipMemsetAsync(d_ws, 0, zero_elems * 4, stream);

    const int TB = (N_EDGES + TILE_E - 1) / TILE_E;   // 391
    const int NB = (N_NODES + 255) / 256;             // 391
    const int HB = N_NODES / 4;                       // 25000 (wave per node)

    bucket_hist_kernel<<<TB, 256, 0, stream>>>(rows, bhist, deg_cnt);
    bucket_scan_kernel<<<1, 256, 0, stream>>>(bhist, bbase, bcursor);
    bin_scatter_kernel<<<TB, 256, 0, stream>>>(rows, cols, bcursor, bins);
    dinv_ccnt_kernel<<<NB, 256, 0, stream>>>(deg_cnt, cl, dinv, ccnt);
    scan1_kernel<<<NB, 256, 0, stream>>>(deg_cnt, row_start, partials, N_NODES);
    scan2_kernel<<<1, 512, 0, stream>>>(partials, NB);
    scan3_kernel<<<NB, 256, 0, stream>>>(row_start, partials, cursor, N_NODES, N_EDGES);
    bin_fill_kernel<<<NBUCK * FILL_SPLIT, 256, 0, stream>>>(bins, bbase, cursor, csr_col);

    prologue_kernel<<<(N_NODES + PRO_TILE - 1) / PRO_TILE, 256, 0, stream>>>(
        (const float4*)x, (const float4*)W, dinv, bufB);

    hop40_kernel<0><<<HB, 256, 0, stream>>>((const float4*)bufB, (float4*)bufA,
                                            row_start, csr_col, dinv, cl, xc_sum);
    hop40_kernel<0><<<HB, 256, 0, stream>>>((const float4*)bufA, (float4*)bufB,
                                            row_start, csr_col, dinv, cl, xc_sum);
    hop40_kernel<1><<<HB, 256, 0, stream>>>((const float4*)bufB, (float4*)nullptr,
                                            row_start, csr_col, dinv, cl, xc_sum);

    epilogue_kernel<<<(N_NODES * (OUT_F / 4) + 255) / 256, 256, 0, stream>>>(
        (const float4*)xc_sum, ccnt, (const float4*)b, cl, (float4*)out);
}

// Round 5
// 489.698 us; speedup vs baseline: 1.3523x; 1.0583x over previous
//
#include <hip/hip_runtime.h>

#define N_NODES    100000
#define N_EDGES    1600000
#define IN_F       64
#define OUT_F      40
#define N_CLUSTERS 10000

#define BUCK_SHIFT 9                                  // 512 rows per bucket
#define NBUCK      ((N_NODES + 511) >> BUCK_SHIFT)    // 196
#define TILE_E     4096
#define EPT        (TILE_E / 256)                     // 16 edges per thread
#define FILL_SPLIT 8

// ---------------------------------------------------------------- bucket histogram + degree count
__global__ void bucket_hist_kernel(const int* __restrict__ rows, int* __restrict__ bhist,
                                   int* __restrict__ deg) {
    __shared__ int lh[NBUCK];
    int t = threadIdx.x;
    for (int i = t; i < NBUCK; i += 256) lh[i] = 0;
    __syncthreads();
    int e0 = blockIdx.x * TILE_E;
    #pragma unroll
    for (int k = 0; k < EPT; ++k) {
        int e = e0 + t + k * 256;
        if (e < N_EDGES) {
            int r = rows[e];
            atomicAdd(&lh[r >> BUCK_SHIFT], 1);
            atomicAdd(&deg[r], 1);                    // 400 KB window, L2-resident
        }
    }
    __syncthreads();
    for (int i = t; i < NBUCK; i += 256) {
        int c = lh[i];
        if (c) atomicAdd(&bhist[i], c);
    }
}

// ---------------------------------------------------------------- bucket scan (exclusive)
__global__ void bucket_scan_kernel(const int* __restrict__ bhist, int* __restrict__ bbase,
                                   int* __restrict__ bcursor) {
    __shared__ int s[256];
    int t = threadIdx.x;
    int v = (t < NBUCK) ? bhist[t] : 0;
    s[t] = v;
    __syncthreads();
    for (int off = 1; off < 256; off <<= 1) {
        int a = (t >= off) ? s[t - off] : 0;
        __syncthreads();
        s[t] += a;
        __syncthreads();
    }
    if (t < NBUCK) { int ex = s[t] - v; bbase[t] = ex; bcursor[t] = ex; }
    if (t == 0) bbase[NBUCK] = N_EDGES;
}

// ---------------------------------------------------------------- bin scatter (LDS-ordered, coalesced out)
__global__ void bin_scatter_kernel(const int* __restrict__ rows, const int* __restrict__ cols,
                                   int* __restrict__ bcursor, uint2* __restrict__ bins) {
    __shared__ uint2 se[TILE_E];
    __shared__ int lh[NBUCK];
    __shared__ int lsc[NBUCK];
    __shared__ int lb[NBUCK];
    __shared__ int sc[256];
    int t = threadIdx.x;
    for (int i = t; i < NBUCK; i += 256) lh[i] = 0;
    __syncthreads();
    int e0 = blockIdx.x * TILE_E;
    int r[EPT], c[EPT], rk[EPT];
    #pragma unroll
    for (int k = 0; k < EPT; ++k) {
        int e = e0 + t + k * 256;
        if (e < N_EDGES) {
            r[k] = rows[e]; c[k] = cols[e];
            rk[k] = atomicAdd(&lh[r[k] >> BUCK_SHIFT], 1);
        } else r[k] = -1;
    }
    __syncthreads();
    int v = (t < NBUCK) ? lh[t] : 0;
    sc[t] = v;
    __syncthreads();
    for (int off = 1; off < 256; off <<= 1) {
        int a = (t >= off) ? sc[t - off] : 0;
        __syncthreads();
        sc[t] += a;
        __syncthreads();
    }
    if (t < NBUCK) {
        lsc[t] = sc[t] - v;
        lb[t] = v ? atomicAdd(&bcursor[t], v) : 0;
    }
    __syncthreads();
    #pragma unroll
    for (int k = 0; k < EPT; ++k) {
        if (r[k] >= 0) {
            int bu = r[k] >> BUCK_SHIFT;
            se[lsc[bu] + rk[k]] = make_uint2((unsigned)r[k], (unsigned)c[k]);
        }
    }
    __syncthreads();
    #pragma unroll
    for (int k = 0; k < EPT; ++k) {
        int idx = k * 256 + t;
        if (e0 + idx < N_EDGES) {
            uint2 u = se[idx];
            int bu = (int)(u.x >> BUCK_SHIFT);
            bins[lb[bu] + (idx - lsc[bu])] = u;
        }
    }
}

// ---------------------------------------------------------------- dinv + cluster counts
__global__ void dinv_ccnt_kernel(const int* __restrict__ deg, const int* __restrict__ cl,
                                 float* __restrict__ dinv, int* __restrict__ ccnt) {
    int i = blockIdx.x * 256 + threadIdx.x;
    if (i < N_NODES) {
        dinv[i] = rsqrtf((float)(deg[i] + 1));
        atomicAdd(&ccnt[cl[i]], 1);
    }
}

// ---------------------------------------------------------------- node scan (exclusive)
__global__ void scan1_kernel(const int* __restrict__ in, int* __restrict__ out,
                             int* __restrict__ partials, int n) {
    __shared__ int s[256];
    int t = threadIdx.x;
    int i = blockIdx.x * 256 + t;
    int v = (i < n) ? in[i] : 0;
    s[t] = v;
    __syncthreads();
    for (int off = 1; off < 256; off <<= 1) {
        int add = (t >= off) ? s[t - off] : 0;
        __syncthreads();
        s[t] += add;
        __syncthreads();
    }
    if (i < n) out[i] = s[t] - v;
    if (t == 255) partials[blockIdx.x] = s[255];
}

__global__ void scan2_kernel(int* __restrict__ p, int nb) {
    __shared__ int s[512];
    int t = threadIdx.x;
    int v = (t < nb) ? p[t] : 0;
    s[t] = v;
    __syncthreads();
    for (int off = 1; off < 512; off <<= 1) {
        int add = (t >= off) ? s[t - off] : 0;
        __syncthreads();
        s[t] += add;
        __syncthreads();
    }
    if (t < nb) p[t] = s[t] - v;
}

__global__ void scan3_kernel(int* __restrict__ row_start, const int* __restrict__ partials,
                             int* __restrict__ cursor, int n, int total) {
    int i = blockIdx.x * 256 + threadIdx.x;
    if (i < n) {
        int v = row_start[i] + partials[blockIdx.x];
        row_start[i] = v;
        cursor[i] = v;
    }
    if (i == 0) row_start[n] = total;
}

// ---------------------------------------------------------------- CSR fill from bins (L2-local window)
__global__ void bin_fill_kernel(const uint2* __restrict__ bins, const int* __restrict__ bbase,
                                int* __restrict__ cursor, int* __restrict__ csr_col) {
    int b = blockIdx.x / FILL_SPLIT;
    int s = blockIdx.x % FILL_SPLIT;
    int lo = bbase[b], hi = bbase[b + 1];
    int n = hi - lo;
    int chunk = (n + FILL_SPLIT - 1) / FILL_SPLIT;
    int beg = lo + s * chunk;
    int end = min(lo + (s + 1) * chunk, hi);
    for (int i = beg + threadIdx.x; i < end; i += 256) {
        uint2 u = bins[i];
        int pos = atomicAdd(&cursor[u.x], 1);
        csr_col[pos] = (int)u.y;
    }
}

// ---------------------------------------------------------------- prologue: z0 = dinv * (x @ W^T)
// one thread per (node, o). W in LDS (stride 65: o/o+32 alias only -> 2-way, free).
// 40 threads/node re-read the same 256 B x row through L1 (block spans ~6 nodes).
__global__ __launch_bounds__(256) void prologue_kernel(
        const float4* __restrict__ x4, const float* __restrict__ W,
        const float* __restrict__ dinv, float* __restrict__ z0) {
    __shared__ float Ws[OUT_F * 65];
    int t = threadIdx.x;
    for (int i = t; i < OUT_F * IN_F; i += 256)
        Ws[(i >> 6) * 65 + (i & 63)] = W[i];
    __syncthreads();
    int idx = blockIdx.x * 256 + t;
    if (idx >= N_NODES * OUT_F) return;
    int node = idx / OUT_F;
    int o = idx - node * OUT_F;
    const float4* xr = x4 + node * 16;
    const float* wr = Ws + o * 65;
    float acc = 0.f;
    #pragma unroll
    for (int k4 = 0; k4 < 16; ++k4) {
        float4 v = xr[k4];
        acc += v.x * wr[k4 * 4 + 0] + v.y * wr[k4 * 4 + 1]
             + v.z * wr[k4 * 4 + 2] + v.w * wr[k4 * 4 + 3];
    }
    z0[idx] = acc * dinv[node];
}

// ---------------------------------------------------------------- 40-dim hop
// wave per node; lane = slot(0..5) x ql(0..9), float4 per lane => 160 B row per slot.
// FINAL=0: out = dinv^2 * ((A+I) z), store.  FINAL=1: dinv scale, atomicAdd into xc[cl].
template<int FINAL>
__global__ __launch_bounds__(256) void hop40_kernel(
        const float4* __restrict__ in4, float4* __restrict__ out4,
        const int* __restrict__ row_start, const int* __restrict__ csr_col,
        const float* __restrict__ dinv, const int* __restrict__ cl,
        float* __restrict__ xc) {
    int node = (blockIdx.x << 2) + (threadIdx.x >> 6);
    int lane = threadIdx.x & 63;
    int slot = lane / 10;                 // 6 => idle lanes 60..63 (still shfl sources)
    int ql = lane - slot * 10;
    int slotj = (slot < 6) ? slot : 1000; // idle slots never pass the j<lim guard
    int beg = row_start[node];
    int end = row_start[node + 1];
    float4 acc = make_float4(0.f, 0.f, 0.f, 0.f);
    if (slot == 0) acc = in4[node * 10 + ql];        // self-loop term
    for (int base = beg; base < end; base += 64) {
        int idx = base + lane;
        int cv = (idx < end) ? csr_col[idx] : 0;
        int lim = min(64, end - base);
        #pragma unroll
        for (int r = 0; r < 11; ++r) {
            int j = r * 6 + slotj;
            int c = __shfl(cv, j & 63);
            if (j < lim) {
                float4 v = in4[c * 10 + ql];
                acc.x += v.x; acc.y += v.y; acc.z += v.z; acc.w += v.w;
            }
        }
    }
    // reduce slots: lanes<30 fold +30; then lanes<10 fold +10 and +20
    float4 t1;
    t1.x = __shfl(acc.x, (lane + 30) & 63); t1.y = __shfl(acc.y, (lane + 30) & 63);
    t1.z = __shfl(acc.z, (lane + 30) & 63); t1.w = __shfl(acc.w, (lane + 30) & 63);
    if (lane < 30) { acc.x += t1.x; acc.y += t1.y; acc.z += t1.z; acc.w += t1.w; }
    float4 t2, t3;
    t2.x = __shfl(acc.x, (lane + 10) & 63); t2.y = __shfl(acc.y, (lane + 10) & 63);
    t2.z = __shfl(acc.z, (lane + 10) & 63); t2.w = __shfl(acc.w, (lane + 10) & 63);
    t3.x = __shfl(acc.x, (lane + 20) & 63); t3.y = __shfl(acc.y, (lane + 20) & 63);
    t3.z = __shfl(acc.z, (lane + 20) & 63); t3.w = __shfl(acc.w, (lane + 20) & 63);
    if (lane < 10) {
        acc.x += t2.x + t3.x; acc.y += t2.y + t3.y;
        acc.z += t2.z + t3.z; acc.w += t2.w + t3.w;
        float d = dinv[node];
        if (FINAL) {
            float* p = xc + cl[node] * OUT_F + ql * 4;
            atomicAdd(p + 0, acc.x * d); atomicAdd(p + 1, acc.y * d);
            atomicAdd(p + 2, acc.z * d); atomicAdd(p + 3, acc.w * d);
        } else {
            float s = d * d;
            acc.x *= s; acc.y *= s; acc.z *= s; acc.w *= s;
            out4[node * 10 + ql] = acc;
        }
    }
}

// ---------------------------------------------------------------- epilogue: out[n] = xc[cl[n]]/cnt + b
__global__ void epilogue_kernel(const float4* __restrict__ xc4, const int* __restrict__ ccnt,
                                const float4* __restrict__ b4, const int* __restrict__ cl,
                                float4* __restrict__ out4) {
    int i = blockIdx.x * 256 + threadIdx.x;
    if (i >= N_NODES * (OUT_F / 4)) return;
    int node = i / 10;
    int q = i - node * 10;
    int c = cl[node];
    float inv = 1.0f / fmaxf((float)ccnt[c], 1.0f);
    float4 v = xc4[c * 10 + q];
    float4 bb = b4[q];
    v.x = v.x * inv + bb.x; v.y = v.y * inv + bb.y;
    v.z = v.z * inv + bb.z; v.w = v.w * inv + bb.w;
    out4[i] = v;
}

// ---------------------------------------------------------------- launch
extern "C" void kernel_launch(void* const* d_in, const int* in_sizes, int n_in,
                              void* d_out, int out_size, void* d_ws, size_t ws_size,
                              hipStream_t stream) {
    const float* x    = (const float*)d_in[0];
    const int*   rows = (const int*)d_in[1];
    const int*   cols = (const int*)d_in[1] + N_EDGES;
    const int*   cl   = (const int*)d_in[2];
    const float* W    = (const float*)d_in[4];
    const float* b    = (const float*)d_in[5];
    float* out = (float*)d_out;

    size_t off = 0;
    auto alloc = [&](size_t elems) -> void* {
        void* p = (char*)d_ws + off * 4;
        off += (elems + 3) & ~(size_t)3;
        return p;
    };
    // zeroed region first (single memset): deg | ccnt | xc_sum | bhist
    int*   deg_cnt = (int*)alloc(N_NODES);
    int*   ccnt    = (int*)alloc(N_CLUSTERS);
    float* xc_sum  = (float*)alloc((size_t)N_CLUSTERS * OUT_F);
    int*   bhist   = (int*)alloc(NBUCK);
    size_t zero_elems = off;
    float* dinv      = (float*)alloc(N_NODES);
    int*   row_start = (int*)alloc(N_NODES + 1);
    int*   cursor    = (int*)alloc(N_NODES);
    int*   csr_col   = (int*)alloc(N_EDGES);
    int*   bbase     = (int*)alloc(NBUCK + 1);
    int*   bcursor   = (int*)alloc(NBUCK);
    int*   partials  = (int*)alloc(512);
    float* bufA      = (float*)alloc((size_t)N_NODES * OUT_F);  // 16 MB
    float* bufB      = (float*)alloc((size_t)N_NODES * OUT_F);  // 16 MB
    uint2* bins      = (uint2*)bufA;   // 12.8 MB alias; consumed by bin_fill before hop1 writes bufA
    (void)ws_size; (void)in_sizes; (void)n_in; (void)out_size;

    hipMemsetAsync(d_ws, 0, zero_elems * 4, stream);

    const int TB = (N_EDGES + TILE_E - 1) / TILE_E;   // 391
    const int NB = (N_NODES + 255) / 256;             // 391
    const int HB = N_NODES / 4;                       // 25000 (wave per node)

    bucket_hist_kernel<<<TB, 256, 0, stream>>>(rows, bhist, deg_cnt);
    bucket_scan_kernel<<<1, 256, 0, stream>>>(bhist, bbase, bcursor);
    bin_scatter_kernel<<<TB, 256, 0, stream>>>(rows, cols, bcursor, bins);
    dinv_ccnt_kernel<<<NB, 256, 0, stream>>>(deg_cnt, cl, dinv, ccnt);
    scan1_kernel<<<NB, 256, 0, stream>>>(deg_cnt, row_start, partials, N_NODES);
    scan2_kernel<<<1, 512, 0, stream>>>(partials, NB);
    scan3_kernel<<<NB, 256, 0, stream>>>(row_start, partials, cursor, N_NODES, N_EDGES);
    bin_fill_kernel<<<NBUCK * FILL_SPLIT, 256, 0, stream>>>(bins, bbase, cursor, csr_col);

    prologue_kernel<<<(N_NODES * OUT_F + 255) / 256, 256, 0, stream>>>(
        (const float4*)x, W, dinv, bufB);

    hop40_kernel<0><<<HB, 256, 0, stream>>>((const float4*)bufB, (float4*)bufA,
                                            row_start, csr_col, dinv, cl, xc_sum);
    hop40_kernel<0><<<HB, 256, 0, stream>>>((const float4*)bufA, (float4*)bufB,
                                            row_start, csr_col, dinv, cl, xc_sum);
    hop40_kernel<1><<<HB, 256, 0, stream>>>((const float4*)bufB, (float4*)nullptr,
                                            row_start, csr_col, dinv, cl, xc_sum);

    epilogue_kernel<<<(N_NODES * (OUT_F / 4) + 255) / 256, 256, 0, stream>>>(
        (const float4*)xc_sum, ccnt, (const float4*)b, cl, (float4*)out);
}